// Round 2
// baseline (4864.421 us; speedup 1.0000x reference)
//
#include <hip/hip_runtime.h>
#include <hip/hip_bf16.h>
#include <stdint.h>

// Problem constants (VanillaRNN): B=64, T=4096, D=256, H=256, O=256, all fp32.
#define TT 4096
#define BBATCH 64
#define DD 256
#define HH 256
#define OO 256

typedef float  f32x4  __attribute__((ext_vector_type(4)));
typedef short  bf16x8 __attribute__((ext_vector_type(8)));
typedef unsigned short u16x4 __attribute__((ext_vector_type(4)));

__device__ __forceinline__ unsigned short f2bf(float f) {
  unsigned u = __float_as_uint(f);
  u += 0x7FFFu + ((u >> 16) & 1u);   // RNE; inputs are finite
  return (unsigned short)(u >> 16);
}
__device__ __forceinline__ float bf2f(unsigned short h) {
  return __uint_as_float(((unsigned)h) << 16);
}
__device__ __forceinline__ float tanh_fast(float s) {
  // tanh(s) = 1 - 2/(exp(2s)+1); exp->inf/0 saturates to +/-1 cleanly.
  float e = __expf(2.f * s);
  return fmaf(-2.f, __builtin_amdgcn_rcpf(e + 1.f), 1.f);
}
union BU { __hip_bfloat162 h2; unsigned u; };
__device__ __forceinline__ unsigned pack_bf2(float a, float b) {
  BU x; x.h2 = __float22bfloat162_rn(make_float2(a, b));
  return x.u;
}

// ---------------------------------------------------------------------------
// K0: Wt[n][k] = bf16(W[k][n]) for W_xh, W_hy, W_hh.
// ---------------------------------------------------------------------------
__global__ void k0_transpose(const float* __restrict__ Wxh, const float* __restrict__ Why,
                             const float* __restrict__ Whh,
                             unsigned short* __restrict__ Wt1, unsigned short* __restrict__ Wt2,
                             unsigned short* __restrict__ Wt3) {
  const int n = blockIdx.x & 255;
  const int k = threadIdx.x;
  const float* src = (blockIdx.x < 256) ? Wxh : (blockIdx.x < 512 ? Why : Whh);
  unsigned short* dst = (blockIdx.x < 256) ? Wt1 : (blockIdx.x < 512 ? Wt2 : Wt3);
  dst[n * 256 + k] = f2bf(src[k * 256 + n]);
}

// ---------------------------------------------------------------------------
// K1: xp[t][b][h] = bf16( x[b][t][:] @ W_xh[:,h] + b_h[h] )   (unchanged)
// ---------------------------------------------------------------------------
__global__ __launch_bounds__(256) void k1_gemm_xp(
    const float* __restrict__ x, const unsigned short* __restrict__ Wt,
    const float* __restrict__ bh, unsigned short* __restrict__ xp) {
  __shared__ __align__(16) unsigned short As[64 * 264];
  const int tid = threadIdx.x;
  const int m0 = blockIdx.x * 64;              // global row m = b*4096 + t

  #pragma unroll
  for (int rr = 0; rr < 16; ++rr) {
    int idx = tid + rr * 256;                  // 0..4095
    int row = idx >> 6;
    int c4  = (idx & 63) << 2;
    f32x4 v = *(const f32x4*)(x + (size_t)(m0 + row) * 256 + c4);
    unsigned w0 = (unsigned)f2bf(v[0]) | ((unsigned)f2bf(v[1]) << 16);
    unsigned w1 = (unsigned)f2bf(v[2]) | ((unsigned)f2bf(v[3]) << 16);
    *(uint2*)(As + row * 264 + c4) = make_uint2(w0, w1);
  }

  const int wv = tid >> 6, ln = tid & 63, l15 = ln & 15, q = ln >> 4;

  bf16x8 bfr[4][8];
  #pragma unroll
  for (int ntl = 0; ntl < 4; ++ntl) {
    #pragma unroll
    for (int kt = 0; kt < 8; ++kt) {
      int n = (wv * 4 + ntl) * 16 + l15;
      int k = kt * 32 + q * 8;
      bfr[ntl][kt] = *(const bf16x8*)(Wt + n * 256 + k);
    }
  }
  float biasv[4];
  #pragma unroll
  for (int ntl = 0; ntl < 4; ++ntl) biasv[ntl] = bh[(wv * 4 + ntl) * 16 + l15];

  __syncthreads();

  #pragma unroll 1
  for (int ms = 0; ms < 4; ++ms) {
    bf16x8 afr[8];
    #pragma unroll
    for (int kt = 0; kt < 8; ++kt)
      afr[kt] = *(const bf16x8*)(As + (ms * 16 + l15) * 264 + kt * 32 + q * 8);
    f32x4 acc[4];
    #pragma unroll
    for (int ntl = 0; ntl < 4; ++ntl) acc[ntl] = (f32x4){0.f, 0.f, 0.f, 0.f};
    #pragma unroll
    for (int ntl = 0; ntl < 4; ++ntl) {
      #pragma unroll
      for (int kt = 0; kt < 8; ++kt)
        acc[ntl] = __builtin_amdgcn_mfma_f32_16x16x32_bf16(afr[kt], bfr[ntl][kt], acc[ntl], 0, 0, 0);
    }
    #pragma unroll
    for (int ntl = 0; ntl < 4; ++ntl) {
      int c = (wv * 4 + ntl) * 16 + l15;
      #pragma unroll
      for (int r = 0; r < 4; ++r) {
        int m = m0 + ms * 16 + q * 4 + r;
        int t = m & 4095, b = m >> 12;
        xp[(size_t)(t * 64 + b) * 256 + c] = f2bf(acc[ntl][r] + biasv[ntl]);
      }
    }
  }
}

// ---------------------------------------------------------------------------
// K2: MFMA recurrence. 4 WGs x 256 thr (4 waves), 16 batch rows per WG.
// Swapped MFMA: A = W_hh^T (static frags in regs), B = h (LDS, dbuf).
//   A-frag: lane row l15 = out-col in tile, k = kt*32 + 8q + e  -> Wt3 rows.
//   B-frag: lane col l15 = batch row,       k same              -> hbuf rows.
//   C:      col = l15 (batch), row-in-tile = 4q + r (out-col)   [m89 layouts].
// Rows padded to 264 bf16 -> b128 reads hit the conflict-free 8-phase min.
// One raw s_barrier + lgkmcnt(0) per step; vmcnt NOT drained (xp prefetch
// and hs stores stay in flight across the barrier).
// ---------------------------------------------------------------------------
#define LROW 264
__global__ __launch_bounds__(256, 1) void k2_rnn_mfma(
    unsigned short* xp_hs,                     // aliased: xp in, hs out (bf16)
    const float* __restrict__ h0,
    const unsigned short* __restrict__ Whh_t,  // [n][k] = W_hh[k][n] bf16
    float* __restrict__ hfin) {
  __shared__ __align__(16) unsigned short hbuf[2][16 * LROW];
  const int tid = threadIdx.x;
  const int wv  = tid >> 6;                    // wave 0..3: out cols [64wv, 64wv+64)
  const int ln  = tid & 63, l15 = ln & 15, q = ln >> 4;
  const int bb  = blockIdx.x * 16;
  const int b   = bb + l15;                    // this lane's batch row

  // static A-frags (W_hh^T): wf[i][kt] covers out-col tile (4wv+i), K-tile kt
  bf16x8 wf[4][8];
  #pragma unroll
  for (int i = 0; i < 4; ++i)
    #pragma unroll
    for (int kt = 0; kt < 8; ++kt)
      wf[i][kt] = *(const bf16x8*)(Whh_t + (size_t)((wv * 4 + i) * 16 + l15) * 256 + kt * 32 + q * 8);

  // init hbuf[0] with bf16(h0): thread -> row r = tid>>4, cols (tid&15)*16..+16
  {
    int r = tid >> 4, c0i = (tid & 15) * 16;
    const float* src = h0 + (size_t)(bb + r) * 256 + c0i;
    #pragma unroll
    for (int j = 0; j < 4; ++j) {
      f32x4 v = *(const f32x4*)(src + 4 * j);
      unsigned lo = (unsigned)f2bf(v[0]) | ((unsigned)f2bf(v[1]) << 16);
      unsigned hi = (unsigned)f2bf(v[2]) | ((unsigned)f2bf(v[3]) << 16);
      *(uint2*)(&hbuf[0][r * LROW + c0i + 4 * j]) = make_uint2(lo, hi);
    }
  }

  // prefetch xp[t=0]
  u16x4 xpn[4];
  #pragma unroll
  for (int i = 0; i < 4; ++i)
    xpn[i] = *(const u16x4*)(xp_hs + (size_t)b * 256 + (wv * 4 + i) * 16 + 4 * q);

  __syncthreads();

  int cur = 0;
  #pragma unroll 1
  for (int t = 0; t < TT; ++t) {
    // B-frags: full h (16 rows x 256) of this WG
    bf16x8 hb[8];
    #pragma unroll
    for (int kt = 0; kt < 8; ++kt)
      hb[kt] = *(const bf16x8*)(&hbuf[cur][l15 * LROW + kt * 32 + q * 8]);

    f32x4 acc[4];
    #pragma unroll
    for (int i = 0; i < 4; ++i) acc[i] = (f32x4){0.f, 0.f, 0.f, 0.f};
    #pragma unroll
    for (int kt = 0; kt < 8; ++kt) {
      #pragma unroll
      for (int i = 0; i < 4; ++i)
        acc[i] = __builtin_amdgcn_mfma_f32_16x16x32_bf16(wf[i][kt], hb[kt], acc[i], 0, 0, 0);
    }

    u16x4 xpc[4];
    #pragma unroll
    for (int i = 0; i < 4; ++i) xpc[i] = xpn[i];
    if (t + 1 < TT) {
      const unsigned short* p = xp_hs + ((size_t)(t + 1) * 64 + b) * 256;
      #pragma unroll
      for (int i = 0; i < 4; ++i)
        xpn[i] = *(const u16x4*)(p + (wv * 4 + i) * 16 + 4 * q);
    }

    unsigned short* wrow  = &hbuf[cur ^ 1][l15 * LROW];
    unsigned short* hsrow = xp_hs + ((size_t)t * 64 + b) * 256;
    #pragma unroll
    for (int i = 0; i < 4; ++i) {
      const int c0 = (wv * 4 + i) * 16 + 4 * q;
      float v0 = tanh_fast(acc[i][0] + bf2f(xpc[i][0]));
      float v1 = tanh_fast(acc[i][1] + bf2f(xpc[i][1]));
      float v2 = tanh_fast(acc[i][2] + bf2f(xpc[i][2]));
      float v3 = tanh_fast(acc[i][3] + bf2f(xpc[i][3]));
      uint2 pk = make_uint2(pack_bf2(v0, v1), pack_bf2(v2, v3));
      *(uint2*)(wrow + c0)  = pk;              // ds_write_b64 (next-step h)
      *(uint2*)(hsrow + c0) = pk;              // hs store (8B, in-place)
      if (t == TT - 1) {
        hfin[(size_t)b * 256 + c0 + 0] = v0;
        hfin[(size_t)b * 256 + c0 + 1] = v1;
        hfin[(size_t)b * 256 + c0 + 2] = v2;
        hfin[(size_t)b * 256 + c0 + 3] = v3;
      }
    }
    asm volatile("s_waitcnt lgkmcnt(0)" ::: "memory");
    __builtin_amdgcn_s_barrier();
    __builtin_amdgcn_sched_barrier(0);
    cur ^= 1;
  }
}

// ---------------------------------------------------------------------------
// K3: out[b][t][o] = hs[t][b][:] @ W_hy[:,o] + b_y[o]   (unchanged)
// ---------------------------------------------------------------------------
__global__ __launch_bounds__(256) void k3_gemm_out(
    const unsigned short* __restrict__ hs, const unsigned short* __restrict__ Wt,
    const float* __restrict__ by, float* __restrict__ out) {
  __shared__ __align__(16) unsigned short As[64 * 264];
  const int tid = threadIdx.x;
  const int m0 = blockIdx.x * 64;              // row m = t*64 + b

  #pragma unroll
  for (int rr = 0; rr < 8; ++rr) {
    int idx = tid + rr * 256;                  // 0..2047
    int row = idx >> 5;
    int c8  = (idx & 31) << 3;
    *(uint4*)(As + row * 264 + c8) = *(const uint4*)(hs + (size_t)(m0 + row) * 256 + c8);
  }

  const int wv = tid >> 6, ln = tid & 63, l15 = ln & 15, q = ln >> 4;

  bf16x8 bfr[4][8];
  #pragma unroll
  for (int ntl = 0; ntl < 4; ++ntl) {
    #pragma unroll
    for (int kt = 0; kt < 8; ++kt) {
      int n = (wv * 4 + ntl) * 16 + l15;
      int k = kt * 32 + q * 8;
      bfr[ntl][kt] = *(const bf16x8*)(Wt + n * 256 + k);
    }
  }
  float biasv[4];
  #pragma unroll
  for (int ntl = 0; ntl < 4; ++ntl) biasv[ntl] = by[(wv * 4 + ntl) * 16 + l15];

  __syncthreads();

  #pragma unroll 1
  for (int ms = 0; ms < 4; ++ms) {
    bf16x8 afr[8];
    #pragma unroll
    for (int kt = 0; kt < 8; ++kt)
      afr[kt] = *(const bf16x8*)(As + (ms * 16 + l15) * 264 + kt * 32 + q * 8);
    f32x4 acc[4];
    #pragma unroll
    for (int ntl = 0; ntl < 4; ++ntl) acc[ntl] = (f32x4){0.f, 0.f, 0.f, 0.f};
    #pragma unroll
    for (int ntl = 0; ntl < 4; ++ntl) {
      #pragma unroll
      for (int kt = 0; kt < 8; ++kt)
        acc[ntl] = __builtin_amdgcn_mfma_f32_16x16x32_bf16(afr[kt], bfr[ntl][kt], acc[ntl], 0, 0, 0);
    }
    #pragma unroll
    for (int ntl = 0; ntl < 4; ++ntl) {
      int c = (wv * 4 + ntl) * 16 + l15;
      #pragma unroll
      for (int r = 0; r < 4; ++r) {
        int m  = m0 + ms * 16 + q * 4 + r;
        int bb = m & 63, t = m >> 6;
        out[(size_t)(bb * 4096 + t) * 256 + c] = acc[ntl][r] + biasv[ntl];
      }
    }
  }
}

// ---------------------------------------------------------------------------
extern "C" void kernel_launch(void* const* d_in, const int* in_sizes, int n_in,
                              void* d_out, int out_size, void* d_ws, size_t ws_size,
                              hipStream_t stream) {
  const float* x   = (const float*)d_in[0];
  const float* h0  = (const float*)d_in[1];
  const float* Wxh = (const float*)d_in[2];
  const float* Whh = (const float*)d_in[3];
  const float* bh  = (const float*)d_in[4];
  const float* Why = (const float*)d_in[5];
  const float* by  = (const float*)d_in[6];
  float* out = (float*)d_out;

  // ws: [xp/hs bf16 : T*B*H = 128MB][Wt1 128KB][Wt2 128KB][Wt3 128KB]
  unsigned short* xp  = (unsigned short*)d_ws;
  unsigned short* Wt1 = xp + (size_t)TT * BBATCH * HH;
  unsigned short* Wt2 = Wt1 + 256 * 256;
  unsigned short* Wt3 = Wt2 + 256 * 256;
  float* hfin = out + (size_t)BBATCH * TT * OO;

  hipLaunchKernelGGL(k0_transpose, dim3(768), dim3(256), 0, stream, Wxh, Why, Whh, Wt1, Wt2, Wt3);
  hipLaunchKernelGGL(k1_gemm_xp,   dim3(4096), dim3(256), 0, stream, x, Wt1, bh, xp);
  hipLaunchKernelGGL(k2_rnn_mfma,  dim3(4),    dim3(256), 0, stream, xp, h0, Wt3, hfin);
  hipLaunchKernelGGL(k3_gemm_out,  dim3(4096), dim3(256), 0, stream, xp, Wt2, by, out);
}